// Round 1
// baseline (769.099 us; speedup 1.0000x reference)
//
#include <hip/hip_runtime.h>
#include <math.h>

#define Bc 4
#define Lc 4096
#define Dc 1024
#define Mtot (Bc*Lc)          // 16384 flattened tokens
#define NSEG 64
#define SEGLEN (Lc/NSEG)      // 64

typedef __attribute__((ext_vector_type(8))) short short8;
typedef __attribute__((ext_vector_type(4))) float floatx4;
typedef unsigned short us;

// ---- workspace layout (bytes) — total ~6.3 MB ----
#define OFF_QH    ((size_t)0)          // 1024x1024 bf16
#define OFF_KH    ((size_t)2097152)
#define OFF_PARTS ((size_t)4194304)    // 3*Mtot f32 (dot,qn,kn)
#define OFF_FLAGS ((size_t)4390912)    // int count + 2048 idx (8448 B)
#define OFF_COSV  ((size_t)4399360)    // Mtot f32
#define OFF_ASEG  ((size_t)4464896)    // 256 f32
#define OFF_BSEG  ((size_t)4465920)    // 1 MB
#define OFF_CARRY ((size_t)5514496)    // 1 MB

// ---------------------------------------------------------------------------
__device__ inline us f2bf(float x) {
    unsigned int u = __float_as_uint(x);
    u += 0x7FFFu + ((u >> 16) & 1u);
    return (us)(u >> 16);
}

// ---------------------------------------------------------------------------
// prep: convert Qw/Kw fp32 -> bf16 (single-product GEMM operand) + zero parts
// ---------------------------------------------------------------------------
__global__ __launch_bounds__(256)
void prep_kernel(const float* __restrict__ Qw, const float* __restrict__ Kw,
                 us* __restrict__ Qh, us* __restrict__ Kh,
                 float* __restrict__ parts, int* __restrict__ flags)
{
    const int bid = blockIdx.x, tid = threadIdx.x;
    if (bid < 512) {
        const float* W = (bid < 256) ? Qw : Kw;
        us* Wh = (bid < 256) ? Qh : Kh;
        const int lb = bid & 255;
        #pragma unroll
        for (int k = 0; k < 4; ++k) {
            const size_t e4 = (size_t)lb*1024 + k*256 + tid;
            const float4 v = *(const float4*)&W[e4*4];
            ushort4 h;
            h.x = f2bf(v.x); h.y = f2bf(v.y); h.z = f2bf(v.z); h.w = f2bf(v.w);
            *(ushort4*)&Wh[e4*4] = h;
        }
    } else {
        const int idx = (bid - 512)*256 + tid;
        if (idx < 3*Mtot) parts[idx] = 0.f;
        if (idx == 0) flags[0] = 0;
    }
}

// ---------------------------------------------------------------------------
// Single-product bf16 MFMA GEMM: q_t = Qw.x_t, k'_t = Kw.x_{t+1}.
// Accumulate dot/|q|^2/|k|^2 into parts[3][Mtot] via atomics.
// Tiles: 128(M) x 128(N), BK=32, A-tile 129 rows (k-GEMM reads row+1).
// XOR granule swizzle ((row>>1)&3) on A and B tiles -> conflict-free ds_read.
// XCD swizzle: 8 bn-WGs sharing one A row-tile land on the same XCD L2.
// LDS: A 129x32 bf16 (8256 B) + 2 weight tiles 128x32 (16 KB) = 24,640 B.
// ---------------------------------------------------------------------------
#define AS1C const __attribute__((address_space(1))) void*
#define AS3P __attribute__((address_space(3))) void*

__global__ __launch_bounds__(256, 2)
void gemm_cos_kernel(const float* __restrict__ X,
                     const us* __restrict__ Qh,
                     const us* __restrict__ Kh,
                     float* __restrict__ parts)
{
    __shared__ __align__(16) us lds[12320];
    us* AsH = lds;                 // 129 x 32 shorts
    us* Bs  = lds + 4128;          // [0..4095]=Q tile, [4096..8191]=K tile

    const int tid  = threadIdx.x;
    const int lane = tid & 63;
    const int wv   = tid >> 6;
    const int wm   = wv >> 1;
    const int wn   = wv & 1;
    // XCD-aware swizzle (1024 % 8 == 0 -> bijective)
    const int swz  = ((blockIdx.x & 7) << 7) | (blockIdx.x >> 3);
    const int bm   = swz >> 3;
    const int bn   = swz & 7;
    const int t0   = bm * 128;
    const int nb   = bn * 128;

    floatx4 accq[4][4], acck[4][4];
    const floatx4 zz = {0.f, 0.f, 0.f, 0.f};
    #pragma unroll
    for (int i = 0; i < 4; i++)
        #pragma unroll
        for (int j = 0; j < 4; j++) { accq[i][j] = zz; acck[i][j] = zz; }

    const int lrow = lane & 15;
    const int lg   = lane >> 4;    // k-granule 0..3 (8 shorts each)

    for (int ch = 0; ch < 32; ++ch) {
        const int k0 = ch << 5;

        // ---- stage A: 129x32 fp32 X -> bf16, swizzled ds_write ----
        for (int g = tid; g < 1032; g += 256) {
            const int row = g >> 3, c4 = g & 7;
            int tt = t0 + row; if (tt >= Mtot) tt = Mtot - 1;   // halo clamp
            const float4 v = *(const float4*)&X[(size_t)tt*Dc + k0 + c4*4];
            ushort4 h;
            h.x = f2bf(v.x); h.y = f2bf(v.y); h.z = f2bf(v.z); h.w = f2bf(v.w);
            const int sw = ((((c4 >> 1) ^ ((row >> 1) & 3)) << 1) | (c4 & 1)) << 2;
            *(ushort4*)&AsH[row*32 + sw] = h;
        }
        // ---- stage B: Q,K bf16 tiles via global_load_lds, source-swizzled ----
        #pragma unroll
        for (int it = 0; it < 4; ++it) {
            const int gb  = it*256 + wv*64;          // wave-uniform granule base
            const int g   = gb + lane;
            const us* wbase = (g & 512) ? Kh : Qh;   // wave-uniform tile select
            const int gg  = g & 511;
            const int row = gg >> 2;
            const int sl  = (gg & 3) ^ ((row >> 1) & 3);
            const us* gp = wbase + (size_t)(nb + row)*Dc + k0 + (sl << 3);
            __builtin_amdgcn_global_load_lds((AS1C)gp, (AS3P)(Bs + gb*8), 16, 0, 0);
        }
        __syncthreads();

        short8 aq[4], ak[4];
        #pragma unroll
        for (int i = 0; i < 4; ++i) {
            const int r  = wm*64 + i*16 + lrow;
            const int r1 = r + 1;
            aq[i] = *(const short8*)&AsH[r *32 + ((lg ^ ((r  >> 1) & 3)) << 3)];
            ak[i] = *(const short8*)&AsH[r1*32 + ((lg ^ ((r1 >> 1) & 3)) << 3)];
        }
        #pragma unroll
        for (int j = 0; j < 4; ++j) {
            const int rn = wn*64 + j*16 + lrow;
            const int bo = rn*32 + ((lg ^ ((rn >> 1) & 3)) << 3);
            const short8 fbq = *(const short8*)&Bs[bo];
            const short8 fbk = *(const short8*)&Bs[4096 + bo];
            #pragma unroll
            for (int i = 0; i < 4; ++i) {
                accq[i][j] = __builtin_amdgcn_mfma_f32_16x16x32_bf16(aq[i], fbq, accq[i][j], 0, 0, 0);
                acck[i][j] = __builtin_amdgcn_mfma_f32_16x16x32_bf16(ak[i], fbk, acck[i][j], 0, 0, 0);
            }
        }
        __syncthreads();
    }

    // ---- epilogue: per-row dot/qn/kn over this WG's 128 cols, then atomics ----
    #pragma unroll
    for (int i = 0; i < 4; ++i) {
        #pragma unroll
        for (int reg = 0; reg < 4; ++reg) {
            float d = 0.f, qq = 0.f, kk = 0.f;
            #pragma unroll
            for (int j = 0; j < 4; ++j) {
                const float qv = accq[i][j][reg];
                const float kv = acck[i][j][reg];
                d  += qv * kv;
                qq += qv * qv;
                kk += kv * kv;
            }
            #pragma unroll
            for (int m = 1; m <= 8; m <<= 1) {
                d  += __shfl_xor(d,  m);
                qq += __shfl_xor(qq, m);
                kk += __shfl_xor(kk, m);
            }
            if ((lane & 15) == 0) {
                const int row = t0 + wm*64 + i*16 + ((lane >> 4) << 2) + reg;
                atomicAdd(&parts[row],          d);
                atomicAdd(&parts[Mtot + row],   qq);
                atomicAdd(&parts[2*Mtot + row], kk);
            }
        }
    }
}

// ---------------------------------------------------------------------------
// finalize cos + flag near-boundary tokens (|cos| < 7.5e-4 ~= 8.4 sigma of the
// single-product bf16 error); zero flagged parts so repair can re-accumulate.
// ---------------------------------------------------------------------------
__global__ __launch_bounds__(256)
void cos_fin_kernel(float* __restrict__ parts,
                    float* __restrict__ cosv,
                    int* __restrict__ flags)
{
    const int t = blockIdx.x*256 + threadIdx.x;
    if (t >= Mtot) return;
    const float dot = parts[t];
    const float qn  = parts[Mtot + t];
    const float kn  = parts[2*Mtot + t];
    const float c = dot / (fmaxf(sqrtf(qn), 1e-12f) * fmaxf(sqrtf(kn), 1e-12f));
    cosv[t] = c;
    if (fabsf(c) < 7.5e-4f && (t & (Lc-1)) != (Lc-1)) {
        const int idx = atomicAdd(flags, 1);
        if (idx < 2048) {
            flags[1 + idx] = t;
            parts[t] = 0.f; parts[Mtot + t] = 0.f; parts[2*Mtot + t] = 0.f;
        }
    }
}

// ---------------------------------------------------------------------------
// batched exact fp32 repair: 256 WGs, each stages 4 Qw rows + 4 Kw rows in LDS
// (32 KB) once, then streams all flagged tokens (no in-loop barriers).
// Wave w handles e = e0+w for both Q (dot x_t) and K (dot x_{t+1}); per-wave
// partials atomicAdd'ed into parts.
// ---------------------------------------------------------------------------
__global__ __launch_bounds__(256)
void repair_kernel(const float* __restrict__ X,
                   const float* __restrict__ Qw,
                   const float* __restrict__ Kw,
                   const int* __restrict__ flags,
                   float* __restrict__ parts)
{
    __shared__ __align__(16) float wrows[8][Dc];   // rows 0-3: Qw, 4-7: Kw
    const int tid  = threadIdx.x;
    const int lane = tid & 63;
    const int wv   = tid >> 6;
    const int e0   = blockIdx.x << 2;

    for (int g = tid; g < 2048; g += 256) {        // 8 rows x 256 float4
        const int rr = g >> 8, c4 = g & 255;
        const float* src = (rr < 4) ? &Qw[(size_t)(e0 + rr)*Dc + c4*4]
                                    : &Kw[(size_t)(e0 + rr - 4)*Dc + c4*4];
        *(float4*)&wrows[rr][c4*4] = *(const float4*)src;
    }
    __syncthreads();

    const int count = min(flags[0], 2048);
    for (int fi = 0; fi < count; ++fi) {
        const int t = flags[1 + fi];
        const float* x0 = &X[(size_t)t*Dc];
        const float* x1 = x0 + Dc;                 // t+1 (never crosses batch: flag excludes l=L-1)
        float s0 = 0.f, s1 = 0.f;
        #pragma unroll
        for (int jj = 0; jj < 4; ++jj) {
            const int idx = (jj*64 + lane) * 4;    // coalesced across lanes
            const float4 a0 = *(const float4*)&x0[idx];
            const float4 a1 = *(const float4*)&x1[idx];
            const float4 w0 = *(const float4*)&wrows[wv][idx];
            const float4 w1 = *(const float4*)&wrows[4 + wv][idx];
            s0 += w0.x*a0.x + w0.y*a0.y + w0.z*a0.z + w0.w*a0.w;
            s1 += w1.x*a1.x + w1.y*a1.y + w1.z*a1.z + w1.w*a1.w;
        }
        #pragma unroll
        for (int m = 1; m < 64; m <<= 1) {
            s0 += __shfl_xor(s0, m);
            s1 += __shfl_xor(s1, m);
        }
        if (lane == 0) {
            atomicAdd(&parts[t],          s0 * s1);
            atomicAdd(&parts[Mtot + t],   s0 * s0);
            atomicAdd(&parts[2*Mtot + t], s1 * s1);
        }
    }
}

__global__ __launch_bounds__(256)
void repair_fin_kernel(const float* __restrict__ parts,
                       const int* __restrict__ flags,
                       float* __restrict__ cosv)
{
    const int i = blockIdx.x*256 + threadIdx.x;
    const int count = min(flags[0], 2048);
    if (i < count) {
        const int t = flags[1 + i];
        const float dot = parts[t];
        const float qn  = parts[Mtot + t];
        const float kn  = parts[2*Mtot + t];
        cosv[t] = dot / (fmaxf(sqrtf(qn), 1e-12f) * fmaxf(sqrtf(kn), 1e-12f));
    }
}

// ---------------------------------------------------------------------------
// EMA scan — branchless (a=1,w=0 when unmasked) so loads are unconditional
// and the compiler can pipeline them at 1-block/CU occupancy.
// ---------------------------------------------------------------------------
__device__ inline void build_seg_coefs(const float* __restrict__ cosv,
                                       int b, int l0,
                                       float* decA, float* wB)
{
    const int tid = threadIdx.x;
    if (tid < SEGLEN) {
        const int l = l0 + tid;
        float p;
        if (l == 0) {
            p = 1.f;
        } else {
            const float c = cosv[b*Lc + l - 1];
            p = fminf(fmaxf((1.f - c) * 0.5f, 0.f), 1.f);
        }
        const bool m = p > 0.5f;
        decA[tid] = m ? (1.f - p) : 1.f;
        wB[tid]   = m ? p : 0.f;
    }
    __syncthreads();
}

__global__ __launch_bounds__(256)
void seg_pass1_kernel(const float* __restrict__ X,
                      const float* __restrict__ cosv,
                      float* __restrict__ Aseg,
                      float* __restrict__ Bseg)
{
    __shared__ float decA[SEGLEN];
    __shared__ float wB[SEGLEN];
    const int tid = threadIdx.x;
    const int b = blockIdx.x >> 6;
    const int s = blockIdx.x & 63;
    const int l0 = s * SEGLEN;
    build_seg_coefs(cosv, b, l0, decA, wB);

    float4 st = make_float4(0.f, 0.f, 0.f, 0.f);
    float A = 1.f;
    const float* xb = X + (size_t)(b*Lc + l0)*Dc + tid*4;
    #pragma unroll 8
    for (int i = 0; i < SEGLEN; i++) {
        const float a = decA[i], w = wB[i];
        const float4 xv = *(const float4*)(xb + (size_t)i*Dc);
        st.x = a*st.x + w*xv.x;
        st.y = a*st.y + w*xv.y;
        st.z = a*st.z + w*xv.z;
        st.w = a*st.w + w*xv.w;
        A *= a;
    }
    *(float4*)&Bseg[(size_t)blockIdx.x*Dc + tid*4] = st;
    if (tid == 0) Aseg[blockIdx.x] = A;
}

__global__ __launch_bounds__(256)
void seg_combine_kernel(const float* __restrict__ Aseg,
                        const float* __restrict__ Bseg,
                        const float* __restrict__ init_state,
                        float* __restrict__ carry)
{
    const int tid = threadIdx.x;
    const int b  = blockIdx.x >> 2;
    const int d  = ((blockIdx.x & 3) << 8) + tid;
    float c = init_state[(size_t)b*Dc + d];
    for (int s = 0; s < NSEG; s++) {
        const size_t idx = (size_t)(b*NSEG + s);
        carry[idx*Dc + d] = c;
        c = Aseg[idx]*c + Bseg[idx*Dc + d];
    }
}

__global__ __launch_bounds__(256)
void seg_pass2_kernel(const float* __restrict__ X,
                      const float* __restrict__ RES,
                      const float* __restrict__ cosv,
                      const float* __restrict__ carry,
                      float* __restrict__ OUT)
{
    __shared__ float decA[SEGLEN];
    __shared__ float wB[SEGLEN];
    const int tid = threadIdx.x;
    const int b = blockIdx.x >> 6;
    const int s = blockIdx.x & 63;
    const int l0 = s * SEGLEN;
    build_seg_coefs(cosv, b, l0, decA, wB);

    float4 st = *(const float4*)&carry[(size_t)blockIdx.x*Dc + tid*4];
    const size_t base = (size_t)(b*Lc + l0)*Dc + tid*4;
    const float* xb = X   + base;
    const float* rb = RES + base;
    float*       ob = OUT + base;
    #pragma unroll 4
    for (int i = 0; i < SEGLEN; i++) {
        const float a = decA[i], w = wB[i];
        const float4 xv = *(const float4*)(xb + (size_t)i*Dc);
        const float4 rv = *(const float4*)(rb + (size_t)i*Dc);
        st.x = a*st.x + w*xv.x;
        st.y = a*st.y + w*xv.y;
        st.z = a*st.z + w*xv.z;
        st.w = a*st.w + w*xv.w;
        float4 ov;
        ov.x = rv.x + st.x;
        ov.y = rv.y + st.y;
        ov.z = rv.z + st.z;
        ov.w = rv.w + st.w;
        *(float4*)(ob + (size_t)i*Dc) = ov;
    }
}

// ---------------------------------------------------------------------------
extern "C" void kernel_launch(void* const* d_in, const int* in_sizes, int n_in,
                              void* d_out, int out_size, void* d_ws, size_t ws_size,
                              hipStream_t stream)
{
    const float* X    = (const float*)d_in[0];
    const float* RES  = (const float*)d_in[1];
    const float* QW   = (const float*)d_in[2];
    const float* KW   = (const float*)d_in[3];
    const float* INIT = (const float*)d_in[4];
    float* OUT = (float*)d_out;

    char* ws = (char*)d_ws;
    us*    Qh    = (us*)   (ws + OFF_QH);
    us*    Kh    = (us*)   (ws + OFF_KH);
    float* parts = (float*)(ws + OFF_PARTS);
    int*   flags = (int*)  (ws + OFF_FLAGS);
    float* cosv  = (float*)(ws + OFF_COSV);
    float* Aseg  = (float*)(ws + OFF_ASEG);
    float* Bseg  = (float*)(ws + OFF_BSEG);
    float* carry = (float*)(ws + OFF_CARRY);

    prep_kernel      <<<704,  256, 0, stream>>>(QW, KW, Qh, Kh, parts, flags);
    gemm_cos_kernel  <<<1024, 256, 0, stream>>>(X, Qh, Kh, parts);
    cos_fin_kernel   <<<64,   256, 0, stream>>>(parts, cosv, flags);
    repair_kernel    <<<256,  256, 0, stream>>>(X, QW, KW, flags, parts);
    repair_fin_kernel<<<8,    256, 0, stream>>>(parts, flags, cosv);
    seg_pass1_kernel  <<<Bc*NSEG, 256, 0, stream>>>(X, cosv, Aseg, Bseg);
    seg_combine_kernel<<<Bc*4,    256, 0, stream>>>(Aseg, Bseg, INIT, carry);
    seg_pass2_kernel  <<<Bc*NSEG, 256, 0, stream>>>(X, RES, cosv, carry, OUT);
}

// Round 2
// 544.579 us; speedup vs baseline: 1.4123x; 1.4123x over previous
//
#include <hip/hip_runtime.h>
#include <math.h>

#define Bc 4
#define Lc 4096
#define Dc 1024
#define Mtot (Bc*Lc)          // 16384 flattened tokens
#define NSEG 64
#define SEGLEN (Lc/NSEG)      // 64

typedef __attribute__((ext_vector_type(8))) short short8;
typedef __attribute__((ext_vector_type(4))) float floatx4;
typedef unsigned short us;

// ---- workspace layout (bytes) — total ~6.3 MB ----
#define OFF_QH    ((size_t)0)          // 1024x1024 bf16
#define OFF_KH    ((size_t)2097152)
#define OFF_PARTS ((size_t)4194304)    // 3*Mtot f32 (dot,qn,kn)
#define OFF_FLAGS ((size_t)4390912)    // int count + 2048 idx (8448 B)
#define OFF_COSV  ((size_t)4399360)    // Mtot f32
#define OFF_ASEG  ((size_t)4464896)    // 256 f32
#define OFF_BSEG  ((size_t)4465920)    // 1 MB
#define OFF_CARRY ((size_t)5514496)    // 1 MB

// ---------------------------------------------------------------------------
__device__ inline us f2bf(float x) {
    unsigned int u = __float_as_uint(x);
    u += 0x7FFFu + ((u >> 16) & 1u);
    return (us)(u >> 16);
}

// ---------------------------------------------------------------------------
// prep: convert Qw/Kw fp32 -> bf16 (single-product GEMM operand) + zero parts
// ---------------------------------------------------------------------------
__global__ __launch_bounds__(256)
void prep_kernel(const float* __restrict__ Qw, const float* __restrict__ Kw,
                 us* __restrict__ Qh, us* __restrict__ Kh,
                 float* __restrict__ parts, int* __restrict__ flags)
{
    const int bid = blockIdx.x, tid = threadIdx.x;
    if (bid < 512) {
        const float* W = (bid < 256) ? Qw : Kw;
        us* Wh = (bid < 256) ? Qh : Kh;
        const int lb = bid & 255;
        #pragma unroll
        for (int k = 0; k < 4; ++k) {
            const size_t e4 = (size_t)lb*1024 + k*256 + tid;
            const float4 v = *(const float4*)&W[e4*4];
            ushort4 h;
            h.x = f2bf(v.x); h.y = f2bf(v.y); h.z = f2bf(v.z); h.w = f2bf(v.w);
            *(ushort4*)&Wh[e4*4] = h;
        }
    } else {
        const int idx = (bid - 512)*256 + tid;
        if (idx < 3*Mtot) parts[idx] = 0.f;
        if (idx == 0) flags[0] = 0;
    }
}

// ---------------------------------------------------------------------------
// Single-product bf16 MFMA GEMM: q_t = Qw.x_t, k'_t = Kw.x_{t+1}.
// Accumulate dot/|q|^2/|k|^2 into parts[3][Mtot] via atomics.
// Tiles: 128(M) x 128(N), BK=32, A-tile 129 rows (k-GEMM reads row+1).
// XOR granule swizzle ((row>>1)&3) on A and B tiles -> conflict-free ds_read.
// XCD swizzle: 8 bn-WGs sharing one A row-tile land on the same XCD L2.
// LDS: A 129x32 bf16 (8256 B) + 2 weight tiles 128x32 (16 KB) = 24,640 B.
// ---------------------------------------------------------------------------
#define AS1C const __attribute__((address_space(1))) void*
#define AS3P __attribute__((address_space(3))) void*

__global__ __launch_bounds__(256, 2)
void gemm_cos_kernel(const float* __restrict__ X,
                     const us* __restrict__ Qh,
                     const us* __restrict__ Kh,
                     float* __restrict__ parts)
{
    __shared__ __align__(16) us lds[12320];
    us* AsH = lds;                 // 129 x 32 shorts
    us* Bs  = lds + 4128;          // [0..4095]=Q tile, [4096..8191]=K tile

    const int tid  = threadIdx.x;
    const int lane = tid & 63;
    const int wv   = tid >> 6;
    const int wm   = wv >> 1;
    const int wn   = wv & 1;
    // XCD-aware swizzle (1024 % 8 == 0 -> bijective)
    const int swz  = ((blockIdx.x & 7) << 7) | (blockIdx.x >> 3);
    const int bm   = swz >> 3;
    const int bn   = swz & 7;
    const int t0   = bm * 128;
    const int nb   = bn * 128;

    floatx4 accq[4][4], acck[4][4];
    const floatx4 zz = {0.f, 0.f, 0.f, 0.f};
    #pragma unroll
    for (int i = 0; i < 4; i++)
        #pragma unroll
        for (int j = 0; j < 4; j++) { accq[i][j] = zz; acck[i][j] = zz; }

    const int lrow = lane & 15;
    const int lg   = lane >> 4;    // k-granule 0..3 (8 shorts each)

    for (int ch = 0; ch < 32; ++ch) {
        const int k0 = ch << 5;

        // ---- stage A: 129x32 fp32 X -> bf16, swizzled ds_write ----
        for (int g = tid; g < 1032; g += 256) {
            const int row = g >> 3, c4 = g & 7;
            int tt = t0 + row; if (tt >= Mtot) tt = Mtot - 1;   // halo clamp
            const float4 v = *(const float4*)&X[(size_t)tt*Dc + k0 + c4*4];
            ushort4 h;
            h.x = f2bf(v.x); h.y = f2bf(v.y); h.z = f2bf(v.z); h.w = f2bf(v.w);
            const int sw = ((((c4 >> 1) ^ ((row >> 1) & 3)) << 1) | (c4 & 1)) << 2;
            *(ushort4*)&AsH[row*32 + sw] = h;
        }
        // ---- stage B: Q,K bf16 tiles via global_load_lds, source-swizzled ----
        #pragma unroll
        for (int it = 0; it < 4; ++it) {
            const int gb  = it*256 + wv*64;          // wave-uniform granule base
            const int g   = gb + lane;
            const us* wbase = (g & 512) ? Kh : Qh;   // wave-uniform tile select
            const int gg  = g & 511;
            const int row = gg >> 2;
            const int sl  = (gg & 3) ^ ((row >> 1) & 3);
            const us* gp = wbase + (size_t)(nb + row)*Dc + k0 + (sl << 3);
            __builtin_amdgcn_global_load_lds((AS1C)gp, (AS3P)(Bs + gb*8), 16, 0, 0);
        }
        __syncthreads();

        short8 aq[4], ak[4];
        #pragma unroll
        for (int i = 0; i < 4; ++i) {
            const int r  = wm*64 + i*16 + lrow;
            const int r1 = r + 1;
            aq[i] = *(const short8*)&AsH[r *32 + ((lg ^ ((r  >> 1) & 3)) << 3)];
            ak[i] = *(const short8*)&AsH[r1*32 + ((lg ^ ((r1 >> 1) & 3)) << 3)];
        }
        #pragma unroll
        for (int j = 0; j < 4; ++j) {
            const int rn = wn*64 + j*16 + lrow;
            const int bo = rn*32 + ((lg ^ ((rn >> 1) & 3)) << 3);
            const short8 fbq = *(const short8*)&Bs[bo];
            const short8 fbk = *(const short8*)&Bs[4096 + bo];
            #pragma unroll
            for (int i = 0; i < 4; ++i) {
                accq[i][j] = __builtin_amdgcn_mfma_f32_16x16x32_bf16(aq[i], fbq, accq[i][j], 0, 0, 0);
                acck[i][j] = __builtin_amdgcn_mfma_f32_16x16x32_bf16(ak[i], fbk, acck[i][j], 0, 0, 0);
            }
        }
        __syncthreads();
    }

    // ---- epilogue: per-row dot/qn/kn over this WG's 128 cols, then atomics ----
    #pragma unroll
    for (int i = 0; i < 4; ++i) {
        #pragma unroll
        for (int reg = 0; reg < 4; ++reg) {
            float d = 0.f, qq = 0.f, kk = 0.f;
            #pragma unroll
            for (int j = 0; j < 4; ++j) {
                const float qv = accq[i][j][reg];
                const float kv = acck[i][j][reg];
                d  += qv * kv;
                qq += qv * qv;
                kk += kv * kv;
            }
            #pragma unroll
            for (int m = 1; m <= 8; m <<= 1) {
                d  += __shfl_xor(d,  m);
                qq += __shfl_xor(qq, m);
                kk += __shfl_xor(kk, m);
            }
            if ((lane & 15) == 0) {
                const int row = t0 + wm*64 + i*16 + ((lane >> 4) << 2) + reg;
                atomicAdd(&parts[row],          d);
                atomicAdd(&parts[Mtot + row],   qq);
                atomicAdd(&parts[2*Mtot + row], kk);
            }
        }
    }
}

// ---------------------------------------------------------------------------
// finalize cos + flag near-boundary tokens (|cos| < 1.2e-3 ~= 12 sigma of the
// single-product bf16 error); zero flagged parts so repair can re-accumulate.
// ---------------------------------------------------------------------------
__global__ __launch_bounds__(256)
void cos_fin_kernel(float* __restrict__ parts,
                    float* __restrict__ cosv,
                    int* __restrict__ flags)
{
    const int t = blockIdx.x*256 + threadIdx.x;
    if (t >= Mtot) return;
    const float dot = parts[t];
    const float qn  = parts[Mtot + t];
    const float kn  = parts[2*Mtot + t];
    const float c = dot / (fmaxf(sqrtf(qn), 1e-12f) * fmaxf(sqrtf(kn), 1e-12f));
    cosv[t] = c;
    if (fabsf(c) < 1.2e-3f && (t & (Lc-1)) != (Lc-1)) {
        const int idx = atomicAdd(flags, 1);
        if (idx < 2048) {
            flags[1 + idx] = t;
            parts[t] = 0.f; parts[Mtot + t] = 0.f; parts[2*Mtot + t] = 0.f;
        }
    }
}

// ---------------------------------------------------------------------------
// batched exact fp32 repair, token-parallel:
//   grid = 1024 WGs = 256 row-groups (rg) x 4 token-groups (tg).
//   Each WG stages 4 Qw rows + 4 Kw rows (32 KB LDS). Each WAVE owns one
//   token per iteration (global token stride 16 = 4 tg x 4 waves) and
//   computes all 8 staged dot-rows for it (8 independent FMA chains -> ILP),
//   then one 8-value shuffle reduce + a single atomic triple per token/WG.
// vs round-1: 4x fewer serial iterations, 4x TLP (16 waves/CU), 4x ILP.
// ---------------------------------------------------------------------------
__global__ __launch_bounds__(256)
void repair_kernel(const float* __restrict__ X,
                   const float* __restrict__ Qw,
                   const float* __restrict__ Kw,
                   const int* __restrict__ flags,
                   float* __restrict__ parts)
{
    __shared__ __align__(16) float wrows[8][Dc];   // rows 0-3: Qw, 4-7: Kw
    const int tid  = threadIdx.x;
    const int lane = tid & 63;
    const int wv   = tid >> 6;
    const int rg   = blockIdx.x & 255;
    const int tg   = blockIdx.x >> 8;              // 0..3
    const int e0   = rg << 2;

    for (int g = tid; g < 2048; g += 256) {        // 8 rows x 256 float4
        const int rr = g >> 8, c4 = g & 255;
        const float* src = (rr < 4) ? &Qw[(size_t)(e0 + rr)*Dc + c4*4]
                                    : &Kw[(size_t)(e0 + rr - 4)*Dc + c4*4];
        *(float4*)&wrows[rr][c4*4] = *(const float4*)src;
    }
    __syncthreads();

    const int count = min(flags[0], 2048);
    for (int fi = tg*4 + wv; fi < count; fi += 16) {
        const int t = flags[1 + fi];
        const float* x0 = &X[(size_t)t*Dc];
        const float* x1 = x0 + Dc;                 // t+1 (flag excludes l=L-1)
        float s0[4] = {0.f,0.f,0.f,0.f}, s1[4] = {0.f,0.f,0.f,0.f};
        #pragma unroll
        for (int jj = 0; jj < 4; ++jj) {
            const int idx = (jj*64 + lane) * 4;    // coalesced across lanes
            const float4 a0 = *(const float4*)&x0[idx];
            const float4 a1 = *(const float4*)&x1[idx];
            #pragma unroll
            for (int r = 0; r < 4; ++r) {
                const float4 w0 = *(const float4*)&wrows[r][idx];
                const float4 w1 = *(const float4*)&wrows[4 + r][idx];
                s0[r] += w0.x*a0.x + w0.y*a0.y + w0.z*a0.z + w0.w*a0.w;
                s1[r] += w1.x*a1.x + w1.y*a1.y + w1.z*a1.z + w1.w*a1.w;
            }
        }
        #pragma unroll
        for (int m = 1; m < 64; m <<= 1) {
            #pragma unroll
            for (int r = 0; r < 4; ++r) {
                s0[r] += __shfl_xor(s0[r], m);
                s1[r] += __shfl_xor(s1[r], m);
            }
        }
        if (lane == 0) {
            float d = 0.f, qq = 0.f, kk = 0.f;
            #pragma unroll
            for (int r = 0; r < 4; ++r) {
                d  += s0[r]*s1[r];
                qq += s0[r]*s0[r];
                kk += s1[r]*s1[r];
            }
            atomicAdd(&parts[t],          d);
            atomicAdd(&parts[Mtot + t],   qq);
            atomicAdd(&parts[2*Mtot + t], kk);
        }
    }
}

__global__ __launch_bounds__(256)
void repair_fin_kernel(const float* __restrict__ parts,
                       const int* __restrict__ flags,
                       float* __restrict__ cosv)
{
    const int i = blockIdx.x*256 + threadIdx.x;
    const int count = min(flags[0], 2048);
    if (i < count) {
        const int t = flags[1 + i];
        const float dot = parts[t];
        const float qn  = parts[Mtot + t];
        const float kn  = parts[2*Mtot + t];
        cosv[t] = dot / (fmaxf(sqrtf(qn), 1e-12f) * fmaxf(sqrtf(kn), 1e-12f));
    }
}

// ---------------------------------------------------------------------------
// EMA scan — branchless (a=1,w=0 when unmasked) so loads are unconditional
// and the compiler can pipeline them at 1-block/CU occupancy.
// ---------------------------------------------------------------------------
__device__ inline void build_seg_coefs(const float* __restrict__ cosv,
                                       int b, int l0,
                                       float* decA, float* wB)
{
    const int tid = threadIdx.x;
    if (tid < SEGLEN) {
        const int l = l0 + tid;
        float p;
        if (l == 0) {
            p = 1.f;
        } else {
            const float c = cosv[b*Lc + l - 1];
            p = fminf(fmaxf((1.f - c) * 0.5f, 0.f), 1.f);
        }
        const bool m = p > 0.5f;
        decA[tid] = m ? (1.f - p) : 1.f;
        wB[tid]   = m ? p : 0.f;
    }
    __syncthreads();
}

__global__ __launch_bounds__(256)
void seg_pass1_kernel(const float* __restrict__ X,
                      const float* __restrict__ cosv,
                      float* __restrict__ Aseg,
                      float* __restrict__ Bseg)
{
    __shared__ float decA[SEGLEN];
    __shared__ float wB[SEGLEN];
    const int tid = threadIdx.x;
    const int b = blockIdx.x >> 6;
    const int s = blockIdx.x & 63;
    const int l0 = s * SEGLEN;
    build_seg_coefs(cosv, b, l0, decA, wB);

    float4 st = make_float4(0.f, 0.f, 0.f, 0.f);
    float A = 1.f;
    const float* xb = X + (size_t)(b*Lc + l0)*Dc + tid*4;
    #pragma unroll 8
    for (int i = 0; i < SEGLEN; i++) {
        const float a = decA[i], w = wB[i];
        const float4 xv = *(const float4*)(xb + (size_t)i*Dc);
        st.x = a*st.x + w*xv.x;
        st.y = a*st.y + w*xv.y;
        st.z = a*st.z + w*xv.z;
        st.w = a*st.w + w*xv.w;
        A *= a;
    }
    *(float4*)&Bseg[(size_t)blockIdx.x*Dc + tid*4] = st;
    if (tid == 0) Aseg[blockIdx.x] = A;
}

__global__ __launch_bounds__(256)
void seg_combine_kernel(const float* __restrict__ Aseg,
                        const float* __restrict__ Bseg,
                        const float* __restrict__ init_state,
                        float* __restrict__ carry)
{
    const int tid = threadIdx.x;
    const int b  = blockIdx.x >> 2;
    const int d  = ((blockIdx.x & 3) << 8) + tid;
    float c = init_state[(size_t)b*Dc + d];
    for (int s = 0; s < NSEG; s++) {
        const size_t idx = (size_t)(b*NSEG + s);
        carry[idx*Dc + d] = c;
        c = Aseg[idx]*c + Bseg[idx*Dc + d];
    }
}

__global__ __launch_bounds__(256)
void seg_pass2_kernel(const float* __restrict__ X,
                      const float* __restrict__ RES,
                      const float* __restrict__ cosv,
                      const float* __restrict__ carry,
                      float* __restrict__ OUT)
{
    __shared__ float decA[SEGLEN];
    __shared__ float wB[SEGLEN];
    const int tid = threadIdx.x;
    const int b = blockIdx.x >> 6;
    const int s = blockIdx.x & 63;
    const int l0 = s * SEGLEN;
    build_seg_coefs(cosv, b, l0, decA, wB);

    float4 st = *(const float4*)&carry[(size_t)blockIdx.x*Dc + tid*4];
    const size_t base = (size_t)(b*Lc + l0)*Dc + tid*4;
    const float* xb = X   + base;
    const float* rb = RES + base;
    float*       ob = OUT + base;
    #pragma unroll 4
    for (int i = 0; i < SEGLEN; i++) {
        const float a = decA[i], w = wB[i];
        const float4 xv = *(const float4*)(xb + (size_t)i*Dc);
        const float4 rv = *(const float4*)(rb + (size_t)i*Dc);
        st.x = a*st.x + w*xv.x;
        st.y = a*st.y + w*xv.y;
        st.z = a*st.z + w*xv.z;
        st.w = a*st.w + w*xv.w;
        float4 ov;
        ov.x = rv.x + st.x;
        ov.y = rv.y + st.y;
        ov.z = rv.z + st.z;
        ov.w = rv.w + st.w;
        *(float4*)(ob + (size_t)i*Dc) = ov;
    }
}

// ---------------------------------------------------------------------------
extern "C" void kernel_launch(void* const* d_in, const int* in_sizes, int n_in,
                              void* d_out, int out_size, void* d_ws, size_t ws_size,
                              hipStream_t stream)
{
    const float* X    = (const float*)d_in[0];
    const float* RES  = (const float*)d_in[1];
    const float* QW   = (const float*)d_in[2];
    const float* KW   = (const float*)d_in[3];
    const float* INIT = (const float*)d_in[4];
    float* OUT = (float*)d_out;

    char* ws = (char*)d_ws;
    us*    Qh    = (us*)   (ws + OFF_QH);
    us*    Kh    = (us*)   (ws + OFF_KH);
    float* parts = (float*)(ws + OFF_PARTS);
    int*   flags = (int*)  (ws + OFF_FLAGS);
    float* cosv  = (float*)(ws + OFF_COSV);
    float* Aseg  = (float*)(ws + OFF_ASEG);
    float* Bseg  = (float*)(ws + OFF_BSEG);
    float* carry = (float*)(ws + OFF_CARRY);

    prep_kernel      <<<704,  256, 0, stream>>>(QW, KW, Qh, Kh, parts, flags);
    gemm_cos_kernel  <<<1024, 256, 0, stream>>>(X, Qh, Kh, parts);
    cos_fin_kernel   <<<64,   256, 0, stream>>>(parts, cosv, flags);
    repair_kernel    <<<1024, 256, 0, stream>>>(X, QW, KW, flags, parts);
    repair_fin_kernel<<<8,    256, 0, stream>>>(parts, flags, cosv);
    seg_pass1_kernel  <<<Bc*NSEG, 256, 0, stream>>>(X, cosv, Aseg, Bseg);
    seg_combine_kernel<<<Bc*4,    256, 0, stream>>>(Aseg, Bseg, INIT, carry);
    seg_pass2_kernel  <<<Bc*NSEG, 256, 0, stream>>>(X, RES, cosv, carry, OUT);
}

// Round 3
// 429.319 us; speedup vs baseline: 1.7914x; 1.2685x over previous
//
#include <hip/hip_runtime.h>
#include <math.h>

#define Bc 4
#define Lc 4096
#define Dc 1024
#define Mtot (Bc*Lc)          // 16384 flattened tokens
#define NSEG 128
#define SEGLEN (Lc/NSEG)      // 32

typedef __attribute__((ext_vector_type(8))) short short8;
typedef __attribute__((ext_vector_type(4))) float floatx4;
typedef unsigned short us;

// ---- workspace layout (bytes) — total ~42.2 MB ----
#define OFF_QH    ((size_t)0)          // 1024x1024 bf16
#define OFF_KH    ((size_t)2097152)
#define OFF_XBF   ((size_t)4194304)    // Mtot x 1024 bf16 (32 MB)
#define OFF_PARTS ((size_t)37748736)   // 3*Mtot f32 (dot,qn,kn)
#define OFF_FLAGS ((size_t)37945344)   // int count + 2048 idx (8448 B)
#define OFF_COSV  ((size_t)37953792)   // Mtot f32
#define OFF_ASEG  ((size_t)38019328)   // Bc*NSEG f32 (2 KB)
#define OFF_BSEG  ((size_t)38021376)   // Bc*NSEG*Dc f32 (2 MB)
#define OFF_CARRY ((size_t)40118528)   // 2 MB

// ---------------------------------------------------------------------------
__device__ inline us f2bf(float x) {
    unsigned int u = __float_as_uint(x);
    u += 0x7FFFu + ((u >> 16) & 1u);
    return (us)(u >> 16);
}

// ---------------------------------------------------------------------------
// prep: Qw/Kw fp32 -> bf16, X fp32 -> bf16 (one-shot, hoisted out of GEMM),
// zero parts + flags.
// ---------------------------------------------------------------------------
__global__ __launch_bounds__(256)
void prep_kernel(const float* __restrict__ Qw, const float* __restrict__ Kw,
                 const float* __restrict__ X,
                 us* __restrict__ Qh, us* __restrict__ Kh, us* __restrict__ Xbf,
                 float* __restrict__ parts, int* __restrict__ flags)
{
    const int bid = blockIdx.x, tid = threadIdx.x;
    if (bid < 512) {
        const float* W = (bid < 256) ? Qw : Kw;
        us* Wh = (bid < 256) ? Qh : Kh;
        const int lb = bid & 255;
        #pragma unroll
        for (int k = 0; k < 4; ++k) {
            const size_t e4 = (size_t)lb*1024 + k*256 + tid;
            const float4 v = *(const float4*)&W[e4*4];
            ushort4 h;
            h.x = f2bf(v.x); h.y = f2bf(v.y); h.z = f2bf(v.z); h.w = f2bf(v.w);
            *(ushort4*)&Wh[e4*4] = h;
        }
    } else if (bid < 704) {
        const int idx = (bid - 512)*256 + tid;
        if (idx < 3*Mtot) parts[idx] = 0.f;
        if (idx == 0) flags[0] = 0;
    } else {
        const int xb = bid - 704;                   // 0..2047
        const float4* src = (const float4*)X;
        ushort4* dst = (ushort4*)Xbf;
        #pragma unroll
        for (int j = 0; j < 8; ++j) {
            const size_t f = (size_t)xb*2048 + j*256 + tid;
            const float4 v = src[f];
            ushort4 h;
            h.x = f2bf(v.x); h.y = f2bf(v.y); h.z = f2bf(v.z); h.w = f2bf(v.w);
            dst[f] = h;
        }
    }
}

// ---------------------------------------------------------------------------
// Single-product bf16 MFMA GEMM: q_t = Qw.x_t, k'_t = Kw.x_{t+1}.
// A (X tile, 129x32, +1-row halo) AND B (Q,K weight tiles) both staged via
// global_load_lds from pre-converted bf16, with pre-swizzled per-lane source
// addresses (granule-XOR (row>>1)&3) -> linear LDS dest, conflict-free reads.
// Per-lane staging pointers precomputed, marched +64B/chunk: ~no in-loop VALU.
// Tiles: 128(M) x 128(N), BK=32. LDS = (516 + 1024) granules = 24,640 B.
// ---------------------------------------------------------------------------
#define AS1C const __attribute__((address_space(1))) void*
#define AS3P __attribute__((address_space(3))) void*

__global__ __launch_bounds__(256, 2)
void gemm_cos_kernel(const us* __restrict__ Xbf,
                     const us* __restrict__ Qh,
                     const us* __restrict__ Kh,
                     float* __restrict__ parts)
{
    __shared__ __align__(16) us lds[12320];
    us* AsH = lds;                 // 516 granules: (row,c) at row*32 + c*8
    us* Bs  = lds + 4128;          // 1024 granules: Q tile then K tile

    const int tid  = threadIdx.x;
    const int lane = tid & 63;
    const int wv   = tid >> 6;
    const int wm   = wv >> 1;
    const int wn   = wv & 1;
    // XCD-aware swizzle (1024 % 8 == 0 -> bijective)
    const int swz  = ((blockIdx.x & 7) << 7) | (blockIdx.x >> 3);
    const int bm   = swz >> 3;
    const int bn   = swz & 7;
    const int t0   = bm * 128;
    const int nb   = bn * 128;

    floatx4 accq[4][4], acck[4][4];
    const floatx4 zz = {0.f, 0.f, 0.f, 0.f};
    #pragma unroll
    for (int i = 0; i < 4; i++)
        #pragma unroll
        for (int j = 0; j < 4; j++) { accq[i][j] = zz; acck[i][j] = zz; }

    // ---- staging source pointers (per-lane, pre-swizzled), marched /chunk ----
    // A granule g: row=g>>2, c=g&3; source column-granule = c ^ ((row>>1)&3)
    const int r0 = tid >> 2, c0 = tid & 3;
    const int r1 = r0 + 64;
    const us* pA0 = Xbf + (size_t)(t0 + r0)*Dc + ((c0 ^ ((r0 >> 1) & 3)) << 3);
    const us* pA1 = Xbf + (size_t)(t0 + r1)*Dc + ((c0 ^ ((r1 >> 1) & 3)) << 3);
    int ta2 = t0 + 128; if (ta2 >= Mtot) ta2 = Mtot - 1;   // halo row clamp
    const us* pA2 = Xbf + (size_t)ta2*Dc + ((tid & 3) << 3); // (128>>1)&3 == 0
    const us* pB[4];
    #pragma unroll
    for (int it = 0; it < 4; ++it) {
        const int g   = it*256 + tid;
        const us* wbase = (g & 512) ? Kh : Qh;
        const int gg  = g & 511;
        const int row = gg >> 2;
        const int sl  = (gg & 3) ^ ((row >> 1) & 3);
        pB[it] = wbase + (size_t)(nb + row)*Dc + (sl << 3);
    }

    const int lrow = lane & 15;
    const int lg   = lane >> 4;    // k-granule 0..3 (8 shorts each)

    for (int ch = 0; ch < 32; ++ch) {
        // ---- stage A + B via global_load_lds (7 issues/thread) ----
        __builtin_amdgcn_global_load_lds((AS1C)pA0, (AS3P)(AsH + tid*8),       16, 0, 0);
        __builtin_amdgcn_global_load_lds((AS1C)pA1, (AS3P)(AsH + (tid+256)*8), 16, 0, 0);
        if (tid < 4)
            __builtin_amdgcn_global_load_lds((AS1C)pA2, (AS3P)(AsH + (tid+512)*8), 16, 0, 0);
        #pragma unroll
        for (int it = 0; it < 4; ++it)
            __builtin_amdgcn_global_load_lds((AS1C)pB[it], (AS3P)(Bs + (it*256 + tid)*8), 16, 0, 0);
        pA0 += 32; pA1 += 32; pA2 += 32;
        pB[0] += 32; pB[1] += 32; pB[2] += 32; pB[3] += 32;
        __syncthreads();

        short8 aq[4], ak[4];
        #pragma unroll
        for (int i = 0; i < 4; ++i) {
            const int r  = wm*64 + i*16 + lrow;
            const int r1f = r + 1;
            aq[i] = *(const short8*)&AsH[r  *32 + ((lg ^ ((r   >> 1) & 3)) << 3)];
            ak[i] = *(const short8*)&AsH[r1f*32 + ((lg ^ ((r1f >> 1) & 3)) << 3)];
        }
        #pragma unroll
        for (int j = 0; j < 4; ++j) {
            const int rn = wn*64 + j*16 + lrow;
            const int bo = rn*32 + ((lg ^ ((rn >> 1) & 3)) << 3);
            const short8 fbq = *(const short8*)&Bs[bo];
            const short8 fbk = *(const short8*)&Bs[4096 + bo];
            #pragma unroll
            for (int i = 0; i < 4; ++i) {
                accq[i][j] = __builtin_amdgcn_mfma_f32_16x16x32_bf16(aq[i], fbq, accq[i][j], 0, 0, 0);
                acck[i][j] = __builtin_amdgcn_mfma_f32_16x16x32_bf16(ak[i], fbk, acck[i][j], 0, 0, 0);
            }
        }
        __syncthreads();
    }

    // ---- epilogue: per-row dot/qn/kn over this WG's 128 cols, then atomics ----
    #pragma unroll
    for (int i = 0; i < 4; ++i) {
        #pragma unroll
        for (int reg = 0; reg < 4; ++reg) {
            float d = 0.f, qq = 0.f, kk = 0.f;
            #pragma unroll
            for (int j = 0; j < 4; ++j) {
                const float qv = accq[i][j][reg];
                const float kv = acck[i][j][reg];
                d  += qv * kv;
                qq += qv * qv;
                kk += kv * kv;
            }
            #pragma unroll
            for (int m = 1; m <= 8; m <<= 1) {
                d  += __shfl_xor(d,  m);
                qq += __shfl_xor(qq, m);
                kk += __shfl_xor(kk, m);
            }
            if ((lane & 15) == 0) {
                const int row = t0 + wm*64 + i*16 + ((lane >> 4) << 2) + reg;
                atomicAdd(&parts[row],          d);
                atomicAdd(&parts[Mtot + row],   qq);
                atomicAdd(&parts[2*Mtot + row], kk);
            }
        }
    }
}

// ---------------------------------------------------------------------------
// finalize cos + flag near-boundary tokens (|cos| < 1.2e-3 ~= 12 sigma of the
// single-product bf16 error); zero flagged parts so repair can re-accumulate.
// ---------------------------------------------------------------------------
__global__ __launch_bounds__(256)
void cos_fin_kernel(float* __restrict__ parts,
                    float* __restrict__ cosv,
                    int* __restrict__ flags)
{
    const int t = blockIdx.x*256 + threadIdx.x;
    if (t >= Mtot) return;
    const float dot = parts[t];
    const float qn  = parts[Mtot + t];
    const float kn  = parts[2*Mtot + t];
    const float c = dot / (fmaxf(sqrtf(qn), 1e-12f) * fmaxf(sqrtf(kn), 1e-12f));
    cosv[t] = c;
    if (fabsf(c) < 1.2e-3f && (t & (Lc-1)) != (Lc-1)) {
        const int idx = atomicAdd(flags, 1);
        if (idx < 2048) {
            flags[1 + idx] = t;
            parts[t] = 0.f; parts[Mtot + t] = 0.f; parts[2*Mtot + t] = 0.f;
        }
    }
}

// ---------------------------------------------------------------------------
// batched exact fp32 repair, token-parallel (1024 WGs = 256 row-groups x 4
// token-groups; each wave owns a token, computes 8 staged dot-rows).
// ---------------------------------------------------------------------------
__global__ __launch_bounds__(256)
void repair_kernel(const float* __restrict__ X,
                   const float* __restrict__ Qw,
                   const float* __restrict__ Kw,
                   const int* __restrict__ flags,
                   float* __restrict__ parts)
{
    __shared__ __align__(16) float wrows[8][Dc];   // rows 0-3: Qw, 4-7: Kw
    const int tid  = threadIdx.x;
    const int lane = tid & 63;
    const int wv   = tid >> 6;
    const int rg   = blockIdx.x & 255;
    const int tg   = blockIdx.x >> 8;              // 0..3
    const int e0   = rg << 2;

    for (int g = tid; g < 2048; g += 256) {        // 8 rows x 256 float4
        const int rr = g >> 8, c4 = g & 255;
        const float* src = (rr < 4) ? &Qw[(size_t)(e0 + rr)*Dc + c4*4]
                                    : &Kw[(size_t)(e0 + rr - 4)*Dc + c4*4];
        *(float4*)&wrows[rr][c4*4] = *(const float4*)src;
    }
    __syncthreads();

    const int count = min(flags[0], 2048);
    for (int fi = tg*4 + wv; fi < count; fi += 16) {
        const int t = flags[1 + fi];
        const float* x0 = &X[(size_t)t*Dc];
        const float* x1 = x0 + Dc;                 // t+1 (flag excludes l=L-1)
        float s0[4] = {0.f,0.f,0.f,0.f}, s1[4] = {0.f,0.f,0.f,0.f};
        #pragma unroll
        for (int jj = 0; jj < 4; ++jj) {
            const int idx = (jj*64 + lane) * 4;    // coalesced across lanes
            const float4 a0 = *(const float4*)&x0[idx];
            const float4 a1 = *(const float4*)&x1[idx];
            #pragma unroll
            for (int r = 0; r < 4; ++r) {
                const float4 w0 = *(const float4*)&wrows[r][idx];
                const float4 w1 = *(const float4*)&wrows[4 + r][idx];
                s0[r] += w0.x*a0.x + w0.y*a0.y + w0.z*a0.z + w0.w*a0.w;
                s1[r] += w1.x*a1.x + w1.y*a1.y + w1.z*a1.z + w1.w*a1.w;
            }
        }
        #pragma unroll
        for (int m = 1; m < 64; m <<= 1) {
            #pragma unroll
            for (int r = 0; r < 4; ++r) {
                s0[r] += __shfl_xor(s0[r], m);
                s1[r] += __shfl_xor(s1[r], m);
            }
        }
        if (lane == 0) {
            float d = 0.f, qq = 0.f, kk = 0.f;
            #pragma unroll
            for (int r = 0; r < 4; ++r) {
                d  += s0[r]*s1[r];
                qq += s0[r]*s0[r];
                kk += s1[r]*s1[r];
            }
            atomicAdd(&parts[t],          d);
            atomicAdd(&parts[Mtot + t],   qq);
            atomicAdd(&parts[2*Mtot + t], kk);
        }
    }
}

__global__ __launch_bounds__(256)
void repair_fin_kernel(const float* __restrict__ parts,
                       const int* __restrict__ flags,
                       float* __restrict__ cosv)
{
    const int i = blockIdx.x*256 + threadIdx.x;
    const int count = min(flags[0], 2048);
    if (i < count) {
        const int t = flags[1 + i];
        const float dot = parts[t];
        const float qn  = parts[Mtot + t];
        const float kn  = parts[2*Mtot + t];
        cosv[t] = dot / (fmaxf(sqrtf(qn), 1e-12f) * fmaxf(sqrtf(kn), 1e-12f));
    }
}

// ---------------------------------------------------------------------------
// EMA scan — branchless; NSEG=128 (SEGLEN=32) halves the serial chain and
// doubles WG count (512 WGs = 2/CU) vs round 2.
// ---------------------------------------------------------------------------
__device__ inline void build_seg_coefs(const float* __restrict__ cosv,
                                       int b, int l0,
                                       float* decA, float* wB)
{
    const int tid = threadIdx.x;
    if (tid < SEGLEN) {
        const int l = l0 + tid;
        float p;
        if (l == 0) {
            p = 1.f;
        } else {
            const float c = cosv[b*Lc + l - 1];
            p = fminf(fmaxf((1.f - c) * 0.5f, 0.f), 1.f);
        }
        const bool m = p > 0.5f;
        decA[tid] = m ? (1.f - p) : 1.f;
        wB[tid]   = m ? p : 0.f;
    }
    __syncthreads();
}

__global__ __launch_bounds__(256)
void seg_pass1_kernel(const float* __restrict__ X,
                      const float* __restrict__ cosv,
                      float* __restrict__ Aseg,
                      float* __restrict__ Bseg)
{
    __shared__ float decA[SEGLEN];
    __shared__ float wB[SEGLEN];
    const int tid = threadIdx.x;
    const int b = blockIdx.x >> 7;
    const int s = blockIdx.x & 127;
    const int l0 = s * SEGLEN;
    build_seg_coefs(cosv, b, l0, decA, wB);

    float4 st = make_float4(0.f, 0.f, 0.f, 0.f);
    float A = 1.f;
    const float* xb = X + (size_t)(b*Lc + l0)*Dc + tid*4;
    #pragma unroll 8
    for (int i = 0; i < SEGLEN; i++) {
        const float a = decA[i], w = wB[i];
        const float4 xv = *(const float4*)(xb + (size_t)i*Dc);
        st.x = a*st.x + w*xv.x;
        st.y = a*st.y + w*xv.y;
        st.z = a*st.z + w*xv.z;
        st.w = a*st.w + w*xv.w;
        A *= a;
    }
    *(float4*)&Bseg[(size_t)blockIdx.x*Dc + tid*4] = st;
    if (tid == 0) Aseg[blockIdx.x] = A;
}

__global__ __launch_bounds__(256)
void seg_combine_kernel(const float* __restrict__ Aseg,
                        const float* __restrict__ Bseg,
                        const float* __restrict__ init_state,
                        float* __restrict__ carry)
{
    const int tid = threadIdx.x;
    const int b  = blockIdx.x >> 2;
    const int d  = ((blockIdx.x & 3) << 8) + tid;
    float c = init_state[(size_t)b*Dc + d];
    for (int s = 0; s < NSEG; s++) {
        const size_t idx = (size_t)(b*NSEG + s);
        carry[idx*Dc + d] = c;
        c = Aseg[idx]*c + Bseg[idx*Dc + d];
    }
}

__global__ __launch_bounds__(256)
void seg_pass2_kernel(const float* __restrict__ X,
                      const float* __restrict__ RES,
                      const float* __restrict__ cosv,
                      const float* __restrict__ carry,
                      float* __restrict__ OUT)
{
    __shared__ float decA[SEGLEN];
    __shared__ float wB[SEGLEN];
    const int tid = threadIdx.x;
    const int b = blockIdx.x >> 7;
    const int s = blockIdx.x & 127;
    const int l0 = s * SEGLEN;
    build_seg_coefs(cosv, b, l0, decA, wB);

    float4 st = *(const float4*)&carry[(size_t)blockIdx.x*Dc + tid*4];
    const size_t base = (size_t)(b*Lc + l0)*Dc + tid*4;
    const float* xb = X   + base;
    const float* rb = RES + base;
    float*       ob = OUT + base;
    #pragma unroll 4
    for (int i = 0; i < SEGLEN; i++) {
        const float a = decA[i], w = wB[i];
        const float4 xv = *(const float4*)(xb + (size_t)i*Dc);
        const float4 rv = *(const float4*)(rb + (size_t)i*Dc);
        st.x = a*st.x + w*xv.x;
        st.y = a*st.y + w*xv.y;
        st.z = a*st.z + w*xv.z;
        st.w = a*st.w + w*xv.w;
        float4 ov;
        ov.x = rv.x + st.x;
        ov.y = rv.y + st.y;
        ov.z = rv.z + st.z;
        ov.w = rv.w + st.w;
        *(float4*)(ob + (size_t)i*Dc) = ov;
    }
}

// ---------------------------------------------------------------------------
extern "C" void kernel_launch(void* const* d_in, const int* in_sizes, int n_in,
                              void* d_out, int out_size, void* d_ws, size_t ws_size,
                              hipStream_t stream)
{
    const float* X    = (const float*)d_in[0];
    const float* RES  = (const float*)d_in[1];
    const float* QW   = (const float*)d_in[2];
    const float* KW   = (const float*)d_in[3];
    const float* INIT = (const float*)d_in[4];
    float* OUT = (float*)d_out;

    char* ws = (char*)d_ws;
    us*    Qh    = (us*)   (ws + OFF_QH);
    us*    Kh    = (us*)   (ws + OFF_KH);
    us*    Xbf   = (us*)   (ws + OFF_XBF);
    float* parts = (float*)(ws + OFF_PARTS);
    int*   flags = (int*)  (ws + OFF_FLAGS);
    float* cosv  = (float*)(ws + OFF_COSV);
    float* Aseg  = (float*)(ws + OFF_ASEG);
    float* Bseg  = (float*)(ws + OFF_BSEG);
    float* carry = (float*)(ws + OFF_CARRY);

    prep_kernel      <<<2752, 256, 0, stream>>>(QW, KW, X, Qh, Kh, Xbf, parts, flags);
    gemm_cos_kernel  <<<1024, 256, 0, stream>>>(Xbf, Qh, Kh, parts);
    cos_fin_kernel   <<<64,   256, 0, stream>>>(parts, cosv, flags);
    repair_kernel    <<<1024, 256, 0, stream>>>(X, QW, KW, flags, parts);
    repair_fin_kernel<<<8,    256, 0, stream>>>(parts, flags, cosv);
    seg_pass1_kernel  <<<Bc*NSEG, 256, 0, stream>>>(X, cosv, Aseg, Bseg);
    seg_combine_kernel<<<Bc*4,    256, 0, stream>>>(Aseg, Bseg, INIT, carry);
    seg_pass2_kernel  <<<Bc*NSEG, 256, 0, stream>>>(X, RES, cosv, carry, OUT);
}